// Round 1
// baseline (1496.101 us; speedup 1.0000x reference)
//
#include <hip/hip_runtime.h>
#include <math.h>

#define NN 10000
#define NE 80000
#define SF 97   // smF row stride (pad: 97%32==1 -> lanes spread across banks)
#define SX 68   // x/h row stride (68%4==0 keeps float4 alignment, 4e+kk bank spread)

// C[e][j] += sum_k x[e][k] * B[k][j]; lane=j, wave owns 16 e-rows (accums in regs).
// x read as wave-uniform broadcast b128; B read as conflict-free spread b32.
__device__ __forceinline__ void gemm_tile(const float* __restrict__ xb,
                                          const float* __restrict__ Bs,
                                          float* __restrict__ acc,
                                          int j, int eb, int nk4) {
  #pragma unroll 1
  for (int kq = 0; kq < nk4; ++kq) {
    const int kk = kq * 4;
    const float w0 = Bs[(kk + 0) * 64 + j];
    const float w1 = Bs[(kk + 1) * 64 + j];
    const float w2 = Bs[(kk + 2) * 64 + j];
    const float w3 = Bs[(kk + 3) * 64 + j];
    #pragma unroll
    for (int m = 0; m < 16; ++m) {
      const float4 xv = *(const float4*)(xb + (eb + m) * SX + kk);
      float a = acc[m];
      a = fmaf(xv.x, w0, a);
      a = fmaf(xv.y, w1, a);
      a = fmaf(xv.z, w2, a);
      a = fmaf(xv.w, w3, a);
      acc[m] = a;
    }
  }
}

__global__ __launch_bounds__(256, 2)
void sgnn_edge(const float* __restrict__ f, const float* __restrict__ s,
               const float* __restrict__ edge_f, const float* __restrict__ edge_s,
               const float* __restrict__ Wemb,
               const float* __restrict__ W1, const float* __restrict__ b1,
               const float* __restrict__ W2, const float* __restrict__ b2,
               const float* __restrict__ W3, const float* __restrict__ b3,
               const int* __restrict__ eidx,
               float* __restrict__ fc_sum, float* __restrict__ sc_sum,
               float* __restrict__ cnt) {
  __shared__ float smF[64 * SF];                 // _f embedded: [le][i*32+a]
  __shared__ __align__(16) float xb[64 * SX];    // x-tile / h1 / h2
  __shared__ float Bs[68 * 64];                  // W-tile (also Wemb1 at start)
  __shared__ float iFn[64];
  __shared__ float red[256];
  __shared__ int e0s[64], e1s[64];

  const int t = threadIdx.x;
  const int j = t & 63;       // lane / output column
  const int w = t >> 6;       // wave id
  const int eb = w * 16;      // wave's edge-row base
  const int bid = blockIdx.x;

  if (t < 64) {
    e0s[t] = eidx[bid * 64 + t];
    e1s[t] = eidx[NE + bid * 64 + t];
  }
  for (int idx = t; idx < 65 * 32; idx += 256) Bs[idx] = Wemb[idx];
  __syncthreads();

  // ---- embed: _f[le][i][:] = concat(f[e0],f[e1],edge_f)[i][:] @ Wemb1 ----
  #pragma unroll 1
  for (int r = 0; r < 24; ++r) {
    const int out = t + 256 * r;        // 6144 = 64*3*32
    const int jj = out & 31;
    const int i = (out >> 5) % 3;
    const int le = out / 96;
    const float* base0 = f + e0s[le] * 96 + i * 32;
    const float* base1 = f + e1s[le] * 96 + i * 32;
    float a = 0.f;
    #pragma unroll
    for (int kq = 0; kq < 8; ++kq) {
      const float4 v = *(const float4*)(base0 + kq * 4);
      a = fmaf(v.x, Bs[(kq * 4 + 0) * 32 + jj], a);
      a = fmaf(v.y, Bs[(kq * 4 + 1) * 32 + jj], a);
      a = fmaf(v.z, Bs[(kq * 4 + 2) * 32 + jj], a);
      a = fmaf(v.w, Bs[(kq * 4 + 3) * 32 + jj], a);
    }
    #pragma unroll
    for (int kq = 0; kq < 8; ++kq) {
      const float4 v = *(const float4*)(base1 + kq * 4);
      a = fmaf(v.x, Bs[(32 + kq * 4 + 0) * 32 + jj], a);
      a = fmaf(v.y, Bs[(32 + kq * 4 + 1) * 32 + jj], a);
      a = fmaf(v.z, Bs[(32 + kq * 4 + 2) * 32 + jj], a);
      a = fmaf(v.w, Bs[(32 + kq * 4 + 3) * 32 + jj], a);
    }
    a = fmaf(edge_f[(bid * 64 + le) * 3 + i], Bs[64 * 32 + jj], a);
    smF[le * SF + i * 32 + jj] = a;
  }

  float acc[16];
  #pragma unroll
  for (int m = 0; m < 16; ++m) acc[m] = 0.f;
  float sumsq = 0.f;

  // ---- GEMM1: h1 = x @ W1, x = [f2s(1024) | s[e0] | s[e1] | edge_s] ----
  #pragma unroll 1
  for (int T = 0; T < 19; ++T) {
    const int wT = (T == 18) ? 68 : 64;
    const int kbase = T * 64;
    __syncthreads();
    #pragma unroll 1
    for (int m = 0; m < 17; ++m) {
      const int kk = w + m * 4;
      if (kk < wT) {
        float v;
        if (T < 16) {
          const int k = kbase + kk;
          const int a_ = k >> 5, b_ = k & 31;
          const float* fr = smF + j * SF;
          v = fmaf(fr[a_], fr[b_],
              fmaf(fr[32 + a_], fr[32 + b_], fr[64 + a_] * fr[64 + b_]));
          sumsq = fmaf(v, v, sumsq);
        } else if (T == 16) v = s[e0s[j] * 64 + kk];
        else if (T == 17)   v = s[e1s[j] * 64 + kk];
        else                v = edge_s[(bid * 64 + j) * 68 + kk];
        xb[j * SX + kk] = v;
        Bs[kk * 64 + j] = W1[(kbase + kk) * 64 + j];
      }
    }
    __syncthreads();
    gemm_tile(xb, Bs, acc, j, eb, wT >> 2);
  }

  // ---- h1 epilogue, Fn reduce, W2 stage ----
  __syncthreads();
  red[w * 64 + j] = sumsq;
  {
    const float bv = b1[j];
    #pragma unroll
    for (int m = 0; m < 16; ++m) {
      xb[(eb + m) * SX + j] = fmaxf(acc[m] + bv, 0.f);
      acc[m] = 0.f;
    }
  }
  #pragma unroll 1
  for (int m = 0; m < 16; ++m) {
    const int kk = w + m * 4;
    Bs[kk * 64 + j] = W2[kk * 64 + j];
  }
  __syncthreads();
  if (t < 64) {
    const float ss = red[t] + red[64 + t] + red[128 + t] + red[192 + t];
    iFn[t] = 1.f / (sqrtf(ss) + 1.f);
  }

  // ---- GEMM2 ----
  gemm_tile(xb, Bs, acc, j, eb, 16);
  __syncthreads();
  {
    const float bv = b2[j];
    #pragma unroll
    for (int m = 0; m < 16; ++m)
      xb[(eb + m) * SX + j] = fmaxf(acc[m] + bv, 0.f);
  }

  // ---- GEMM3 (17 n-tiles of 64) + fused consume ----
  float fcp[48];
  #pragma unroll
  for (int q = 0; q < 48; ++q) fcp[q] = 0.f;

  #pragma unroll 1
  for (int nt = 0; nt < 17; ++nt) {
    const int n0 = nt * 64;
    __syncthreads();
    #pragma unroll 1
    for (int m = 0; m < 16; ++m) {
      const int kk = w + m * 4;
      Bs[kk * 64 + j] = W3[kk * 1088 + n0 + j];
    }
    __syncthreads();
    #pragma unroll
    for (int m = 0; m < 16; ++m) acc[m] = 0.f;
    gemm_tile(xb, Bs, acc, j, eb, 16);
    const float bv = b3[n0 + j];
    if (nt < 16) {
      const int a_ = nt * 2 + (j >> 5);   // row of C2; b = j&31 fixed per lane
      #pragma unroll
      for (int m = 0; m < 16; ++m) {
        const float cv = (acc[m] + bv) * iFn[eb + m];
        const float* fr = smF + (eb + m) * SF;
        fcp[m * 3 + 0] = fmaf(fr[a_],      cv, fcp[m * 3 + 0]);
        fcp[m * 3 + 1] = fmaf(fr[32 + a_], cv, fcp[m * 3 + 1]);
        fcp[m * 3 + 2] = fmaf(fr[64 + a_], cv, fcp[m * 3 + 2]);
      }
    } else {
      #pragma unroll 1
      for (int m = 0; m < 16; ++m) {
        const float cv = (acc[m] + bv) * iFn[eb + m];
        atomicAdd(sc_sum + e0s[eb + m] * 64 + j, cv);
      }
    }
  }

  // ---- reduce a-halves across lane pairs (j, j^32), then atomics ----
  {
    const int b_ = j & 31;
    #pragma unroll 1
    for (int m = 0; m < 16; ++m) {
      const int e0 = e0s[eb + m];
      #pragma unroll
      for (int i = 0; i < 3; ++i) {
        float v = fcp[m * 3 + i];
        v += __shfl_xor(v, 32);
        if (j < 32) atomicAdd(fc_sum + e0 * 96 + i * 32 + b_, v);
      }
    }
  }
  if (t < 64) atomicAdd(cnt + e0s[t], 1.0f);
}

__global__ __launch_bounds__(256, 2)
void sgnn_node(const float* __restrict__ f, const float* __restrict__ s,
               const float* __restrict__ Wemb,
               const float* __restrict__ W1, const float* __restrict__ b1,
               const float* __restrict__ W2, const float* __restrict__ b2,
               const float* __restrict__ W3, const float* __restrict__ b3,
               const float* __restrict__ fc_sum, const float* __restrict__ sc_sum,
               const float* __restrict__ cnt,
               float* __restrict__ of, float* __restrict__ os) {
  __shared__ float smF[64 * SF];
  __shared__ __align__(16) float xb[64 * SX];
  __shared__ float Bs[68 * 64];
  __shared__ float iFn[64];
  __shared__ float red[256];
  __shared__ float icnt[64];

  const int t = threadIdx.x;
  const int j = t & 63;
  const int w = t >> 6;
  const int eb = w * 16;
  const int nbase = blockIdx.x * 64;

  if (t < 64) {
    const int nc = min(nbase + t, NN - 1);
    icnt[t] = 1.f / fmaxf(cnt[nc], 1.f);
  }
  for (int idx = t; idx < 64 * 32; idx += 256) Bs[idx] = Wemb[idx];
  __syncthreads();

  // ---- embed: tf = concat(f, f_c) @ Wemb2 ----
  #pragma unroll 1
  for (int r = 0; r < 24; ++r) {
    const int out = t + 256 * r;
    const int jj = out & 31;
    const int i = (out >> 5) % 3;
    const int le = out / 96;
    const int nc = min(nbase + le, NN - 1);
    const float* base0 = f + nc * 96 + i * 32;
    const float* basec = fc_sum + nc * 96 + i * 32;
    const float ic = icnt[le];
    float a = 0.f;
    #pragma unroll
    for (int kq = 0; kq < 8; ++kq) {
      const float4 v = *(const float4*)(base0 + kq * 4);
      a = fmaf(v.x, Bs[(kq * 4 + 0) * 32 + jj], a);
      a = fmaf(v.y, Bs[(kq * 4 + 1) * 32 + jj], a);
      a = fmaf(v.z, Bs[(kq * 4 + 2) * 32 + jj], a);
      a = fmaf(v.w, Bs[(kq * 4 + 3) * 32 + jj], a);
    }
    #pragma unroll
    for (int kq = 0; kq < 8; ++kq) {
      const float4 v = *(const float4*)(basec + kq * 4);
      a = fmaf(v.x * ic, Bs[(32 + kq * 4 + 0) * 32 + jj], a);
      a = fmaf(v.y * ic, Bs[(32 + kq * 4 + 1) * 32 + jj], a);
      a = fmaf(v.z * ic, Bs[(32 + kq * 4 + 2) * 32 + jj], a);
      a = fmaf(v.w * ic, Bs[(32 + kq * 4 + 3) * 32 + jj], a);
    }
    smF[le * SF + i * 32 + jj] = a;
  }

  float acc[16];
  #pragma unroll
  for (int m = 0; m < 16; ++m) acc[m] = 0.f;
  float sumsq = 0.f;

  // ---- GEMM1: x = [tf2s(1024) | s | s_c], 18 tiles of 64 ----
  #pragma unroll 1
  for (int T = 0; T < 18; ++T) {
    const int kbase = T * 64;
    __syncthreads();
    {
      const int nc = min(nbase + j, NN - 1);
      #pragma unroll 1
      for (int m = 0; m < 16; ++m) {
        const int kk = w + m * 4;
        float v;
        if (T < 16) {
          const int k = kbase + kk;
          const int a_ = k >> 5, b_ = k & 31;
          const float* fr = smF + j * SF;
          v = fmaf(fr[a_], fr[b_],
              fmaf(fr[32 + a_], fr[32 + b_], fr[64 + a_] * fr[64 + b_]));
          sumsq = fmaf(v, v, sumsq);
        } else if (T == 16) v = s[nc * 64 + kk];
        else                v = sc_sum[nc * 64 + kk] * icnt[j];
        xb[j * SX + kk] = v;
        Bs[kk * 64 + j] = W1[(kbase + kk) * 64 + j];
      }
    }
    __syncthreads();
    gemm_tile(xb, Bs, acc, j, eb, 16);
  }

  __syncthreads();
  red[w * 64 + j] = sumsq;
  {
    const float bv = b1[j];
    #pragma unroll
    for (int m = 0; m < 16; ++m) {
      xb[(eb + m) * SX + j] = fmaxf(acc[m] + bv, 0.f);
      acc[m] = 0.f;
    }
  }
  #pragma unroll 1
  for (int m = 0; m < 16; ++m) {
    const int kk = w + m * 4;
    Bs[kk * 64 + j] = W2[kk * 64 + j];
  }
  __syncthreads();
  if (t < 64) {
    const float ss = red[t] + red[64 + t] + red[128 + t] + red[192 + t];
    iFn[t] = 1.f / (sqrtf(ss) + 1.f);
  }

  gemm_tile(xb, Bs, acc, j, eb, 16);
  __syncthreads();
  {
    const float bv = b2[j];
    #pragma unroll
    for (int m = 0; m < 16; ++m)
      xb[(eb + m) * SX + j] = fmaxf(acc[m] + bv, 0.f);
  }

  float fcp[48];
  #pragma unroll
  for (int q = 0; q < 48; ++q) fcp[q] = 0.f;

  #pragma unroll 1
  for (int nt = 0; nt < 17; ++nt) {
    const int n0 = nt * 64;
    __syncthreads();
    #pragma unroll 1
    for (int m = 0; m < 16; ++m) {
      const int kk = w + m * 4;
      Bs[kk * 64 + j] = W3[kk * 1088 + n0 + j];
    }
    __syncthreads();
    #pragma unroll
    for (int m = 0; m < 16; ++m) acc[m] = 0.f;
    gemm_tile(xb, Bs, acc, j, eb, 16);
    const float bv = b3[n0 + j];
    if (nt < 16) {
      const int a_ = nt * 2 + (j >> 5);
      #pragma unroll
      for (int m = 0; m < 16; ++m) {
        const float cv = (acc[m] + bv) * iFn[eb + m];
        const float* fr = smF + (eb + m) * SF;
        fcp[m * 3 + 0] = fmaf(fr[a_],      cv, fcp[m * 3 + 0]);
        fcp[m * 3 + 1] = fmaf(fr[32 + a_], cv, fcp[m * 3 + 1]);
        fcp[m * 3 + 2] = fmaf(fr[64 + a_], cv, fcp[m * 3 + 2]);
      }
    } else {
      #pragma unroll 1
      for (int m = 0; m < 16; ++m) {
        const int n_m = nbase + eb + m;
        const float cv = (acc[m] + bv) * iFn[eb + m];
        if (n_m < NN) os[n_m * 64 + j] = cv + s[n_m * 64 + j];
      }
    }
  }

  {
    const int b_ = j & 31;
    #pragma unroll 1
    for (int m = 0; m < 16; ++m) {
      const int n_m = nbase + eb + m;
      #pragma unroll
      for (int i = 0; i < 3; ++i) {
        float v = fcp[m * 3 + i];
        v += __shfl_xor(v, 32);
        if (j < 32 && n_m < NN)
          of[n_m * 96 + i * 32 + b_] = v + f[n_m * 96 + i * 32 + b_];
      }
    }
  }
}

extern "C" void kernel_launch(void* const* d_in, const int* in_sizes, int n_in,
                              void* d_out, int out_size, void* d_ws, size_t ws_size,
                              hipStream_t stream) {
  const float* f      = (const float*)d_in[0];
  const float* s      = (const float*)d_in[1];
  const float* edge_f = (const float*)d_in[2];
  const float* edge_s = (const float*)d_in[3];
  const float* Wemb1  = (const float*)d_in[4];
  const float* nW1 = (const float*)d_in[5];
  const float* nb1 = (const float*)d_in[6];
  const float* nW2 = (const float*)d_in[7];
  const float* nb2 = (const float*)d_in[8];
  const float* nW3 = (const float*)d_in[9];
  const float* nb3 = (const float*)d_in[10];
  const float* Wemb2 = (const float*)d_in[11];
  const float* sW1 = (const float*)d_in[12];
  const float* sb1 = (const float*)d_in[13];
  const float* sW2 = (const float*)d_in[14];
  const float* sb2 = (const float*)d_in[15];
  const float* sW3 = (const float*)d_in[16];
  const float* sb3 = (const float*)d_in[17];
  const int* eidx  = (const int*)d_in[18];

  float* fc_sum = (float*)d_ws;            // [NN*96]
  float* sc_sum = fc_sum + (size_t)NN * 96; // [NN*64]
  float* cntp   = sc_sum + (size_t)NN * 64; // [NN]
  hipMemsetAsync(d_ws, 0, (size_t)NN * 161 * sizeof(float), stream);

  float* of = (float*)d_out;               // [NN*96]
  float* os = of + (size_t)NN * 96;        // [NN*64]

  hipLaunchKernelGGL(sgnn_edge, dim3(NE / 64), dim3(256), 0, stream,
                     f, s, edge_f, edge_s, Wemb1,
                     nW1, nb1, nW2, nb2, nW3, nb3,
                     eidx, fc_sum, sc_sum, cntp);
  hipLaunchKernelGGL(sgnn_node, dim3((NN + 63) / 64), dim3(256), 0, stream,
                     f, s, Wemb2,
                     sW1, sb1, sW2, sb2, sW3, sb3,
                     fc_sum, sc_sum, cntp, of, os);
}